// Round 18
// baseline (523.681 us; speedup 1.0000x reference)
//
#include <hip/hip_runtime.h>
#include <hip/hip_bf16.h>
#include <hip/hip_fp16.h>

typedef float f32x4 __attribute__((ext_vector_type(4)));
typedef _Float16 f16x8 __attribute__((ext_vector_type(8)));
typedef unsigned int u32x4 __attribute__((ext_vector_type(4)));

static constexpr int Bb = 8, Ll = 8192, Hh = 512, Ee = 8, Ff = 1024, KK = 2048;

static __device__ __forceinline__ float fast_rcp(float x) {
#if __has_builtin(__builtin_amdgcn_rcpf)
  return __builtin_amdgcn_rcpf(x);
#else
  return 1.0f / x;
#endif
}

// exact GELU via Abramowitz-Stegun 7.1.25 erf approximation (|err| < 2.5e-5), branchless
static __device__ __forceinline__ float gelu_exact(float v) {
  float a = __builtin_fabsf(v) * 0.70710678118654752f;
  float t = fast_rcp(__builtin_fmaf(0.47047f, a, 1.0f));
  float p = __builtin_fmaf(0.7478556f, t, -0.0958798f);
  p = __builtin_fmaf(p, t, 0.3480242f);
  p = p * t;
  float e = __expf(-a * a);
  float er = __builtin_fmaf(-p, e, 1.0f);
  er = __builtin_copysignf(er, v);
  return 0.5f * v * (1.0f + er);
}

static __device__ __forceinline__ void nt_store16(const f16x8& v, _Float16* p) {
  __builtin_nontemporal_store(*reinterpret_cast<const u32x4*>(&v),
                              reinterpret_cast<u32x4*>(p));
}

// ---------------- transpose + convert: src[z][R][C] f32 -> dst[z][C][R] f16 ----------------
__global__ __launch_bounds__(256) void transpose_cvt_kernel(const float* __restrict__ src,
                                                            _Float16* __restrict__ dst,
                                                            int R, int C) {
  __shared__ float tile[32][33];
  int z = blockIdx.z;
  const float* s = src + (size_t)z * R * C;
  _Float16* d = dst + (size_t)z * R * C;
  int c0 = blockIdx.x * 32, r0 = blockIdx.y * 32;
  int tx = threadIdx.x, ty = threadIdx.y;
#pragma unroll
  for (int i = ty; i < 32; i += 8) tile[i][tx] = s[(size_t)(r0 + i) * C + (c0 + tx)];
  __syncthreads();
#pragma unroll
  for (int i = ty; i < 32; i += 8) d[(size_t)(c0 + i) * R + (r0 + tx)] = (_Float16)tile[tx][i];
}

// ------ fused gate + x->f16 convert; 8 independent fp64 chains, 128-wide chunks ------
__global__ __launch_bounds__(256) void gatecvt_kernel(const float* __restrict__ x,
                                                      const float* __restrict__ Wg,
                                                      double* __restrict__ St,
                                                      _Float16* __restrict__ xb) {
  __shared__ float wgt[8][516];  // Wg transposed, row-padded
  __shared__ float xs[32][132];  // 32 tokens x 128-col chunk, row-padded
  int tid = threadIdx.x;
  for (int i = tid; i < Hh * Ee; i += 256) wgt[i & 7][i >> 3] = Wg[i];
  int row = tid >> 3, seg = tid & 7;
  int token0 = blockIdx.x * 32;
  const float* xrow = x + (size_t)(token0 + row) * Hh;
  _Float16* xbrow = xb + (size_t)(token0 + row) * Hh;
  float4 r0 = reinterpret_cast<const float4*>(xrow)[seg * 4 + 0];
  float4 r1 = reinterpret_cast<const float4*>(xrow)[seg * 4 + 1];
  float4 r2 = reinterpret_cast<const float4*>(xrow)[seg * 4 + 2];
  float4 r3 = reinterpret_cast<const float4*>(xrow)[seg * 4 + 3];
  double a0 = 0.0, a1 = 0.0, a2 = 0.0, a3 = 0.0;  // 8 independent fp64 chains
  double a4 = 0.0, a5 = 0.0, a6 = 0.0, a7 = 0.0;  // (halved dependency depth)
  for (int c = 0; c < 4; ++c) {
    f16x8 h0, h1;
    h0[0] = (_Float16)r0.x; h0[1] = (_Float16)r0.y; h0[2] = (_Float16)r0.z; h0[3] = (_Float16)r0.w;
    h0[4] = (_Float16)r1.x; h0[5] = (_Float16)r1.y; h0[6] = (_Float16)r1.z; h0[7] = (_Float16)r1.w;
    h1[0] = (_Float16)r2.x; h1[1] = (_Float16)r2.y; h1[2] = (_Float16)r2.z; h1[3] = (_Float16)r2.w;
    h1[4] = (_Float16)r3.x; h1[5] = (_Float16)r3.y; h1[6] = (_Float16)r3.z; h1[7] = (_Float16)r3.w;
    nt_store16(h0, xbrow + c * 128 + seg * 16);
    nt_store16(h1, xbrow + c * 128 + seg * 16 + 8);
    __syncthreads();
    *reinterpret_cast<float4*>(&xs[row][seg * 16 + 0]) = r0;
    *reinterpret_cast<float4*>(&xs[row][seg * 16 + 4]) = r1;
    *reinterpret_cast<float4*>(&xs[row][seg * 16 + 8]) = r2;
    *reinterpret_cast<float4*>(&xs[row][seg * 16 + 12]) = r3;
    if (c + 1 < 4) {
      const float4* nx = reinterpret_cast<const float4*>(xrow + (c + 1) * 128);
      r0 = nx[seg * 4 + 0]; r1 = nx[seg * 4 + 1]; r2 = nx[seg * 4 + 2]; r3 = nx[seg * 4 + 3];
    }
    __syncthreads();
#pragma unroll
    for (int hh = 0; hh < 128; hh += 8) {
      float4 xv = *reinterpret_cast<const float4*>(&xs[row][hh]);
      float4 wv = *reinterpret_cast<const float4*>(&wgt[seg][c * 128 + hh]);
      a0 += (double)xv.x * (double)wv.x;
      a1 += (double)xv.y * (double)wv.y;
      a2 += (double)xv.z * (double)wv.z;
      a3 += (double)xv.w * (double)wv.w;
      float4 xw = *reinterpret_cast<const float4*>(&xs[row][hh + 4]);
      float4 ww = *reinterpret_cast<const float4*>(&wgt[seg][c * 128 + hh + 4]);
      a4 += (double)xw.x * (double)ww.x;
      a5 += (double)xw.y * (double)ww.y;
      a6 += (double)xw.z * (double)ww.z;
      a7 += (double)xw.w * (double)ww.w;
    }
  }
  double acc = ((a0 + a1) + (a2 + a3)) + ((a4 + a5) + (a6 + a7));
  double m = acc;
  m = fmax(m, __shfl_xor(m, 1, 64));
  m = fmax(m, __shfl_xor(m, 2, 64));
  m = fmax(m, __shfl_xor(m, 4, 64));
  double ex = exp(acc - m);
  double s = ex;
  s += __shfl_xor(s, 1, 64);
  s += __shfl_xor(s, 2, 64);
  s += __shfl_xor(s, 4, 64);
  int token = token0 + row;
  int b = token >> 13, l = token & (Ll - 1);
  St[((size_t)(b * Ee + seg)) * Ll + l] = ex / s;
}

// ---------------- top-k (k=2048) per (b,e) row, jax.lax.top_k tie semantics ----------------
__global__ __launch_bounds__(1024) void topk_kernel(const double* __restrict__ St,
                                                    int* __restrict__ idx,
                                                    float* __restrict__ gate) {
  __shared__ unsigned long long keys[Ll];
  __shared__ unsigned int hist[256];
  __shared__ unsigned int sc[1024];
  __shared__ unsigned long long s_prefix;
  __shared__ int s_remaining;
  __shared__ unsigned long long redA[16], redO[16];
  int row = blockIdx.x;
  int tid = threadIdx.x;
  const double* s = St + (size_t)row * Ll;
  unsigned long long myA = ~0ULL, myO = 0ULL;
  for (int i = tid; i < Ll; i += 1024) {
    unsigned long long kx = (unsigned long long)__double_as_longlong(s[i]);
    keys[i] = kx;
    myA &= kx;
    myO |= kx;
  }
#pragma unroll
  for (int off2 = 32; off2 >= 1; off2 >>= 1) {
    myA &= __shfl_xor(myA, off2, 64);
    myO |= __shfl_xor(myO, off2, 64);
  }
  if ((tid & 63) == 0) { redA[tid >> 6] = myA; redO[tid >> 6] = myO; }
  __syncthreads();
  unsigned long long allA = redA[0], allO = redO[0];
#pragma unroll
  for (int w = 1; w < 16; ++w) { allA &= redA[w]; allO |= redO[w]; }
  unsigned long long diff = allA ^ allO;

  unsigned long long T;
  int nEqTake;
  if (diff == 0) {
    T = allA;
    nEqTake = KK;
  } else {
    int hb = 63 - __builtin_clzll(diff);
    int pv = hb >> 3;
    unsigned long long prefmask = (pv >= 7) ? 0ULL : (~0ULL << ((pv + 1) * 8));
    unsigned long long prefix = allA & prefmask;
    int remaining = KK;
    for (int p = pv; p >= 0; --p) {
      if (tid < 256) hist[tid] = 0;
      __syncthreads();
      int sh = p * 8;
      for (int i = tid; i < Ll; i += 1024) {
        unsigned long long kk = keys[i];
        if ((kk & prefmask) == prefix) atomicAdd(&hist[(unsigned)(kk >> sh) & 255u], 1u);
      }
      __syncthreads();
      if (tid < 256) sc[tid] = hist[tid];
      __syncthreads();
#pragma unroll
      for (int off = 1; off < 256; off <<= 1) {
        unsigned v = (tid < 256 && tid + off < 256) ? sc[tid + off] : 0;
        __syncthreads();
        if (tid < 256) sc[tid] += v;
        __syncthreads();
      }
      if (tid < 256) {
        unsigned incl = sc[tid];
        unsigned above = (tid == 255) ? 0u : sc[tid + 1];
        if ((int)incl >= remaining && (int)above < remaining) {
          s_remaining = remaining - (int)above;
          s_prefix = prefix | ((unsigned long long)(unsigned)tid << sh);
        }
      }
      __syncthreads();
      remaining = s_remaining;
      prefix = s_prefix;
      prefmask |= (255ULL << sh);
      __syncthreads();
    }
    T = prefix;
    nEqTake = remaining;
  }

  int base = tid * 8;
  unsigned long long kk[8];
  unsigned gtc = 0, eqc = 0;
#pragma unroll
  for (int j = 0; j < 8; ++j) {
    kk[j] = keys[base + j];
    gtc += (kk[j] > T);
    eqc += (kk[j] == T);
  }
  unsigned packed = (gtc << 16) | eqc;
  sc[tid] = packed;
  __syncthreads();
  for (int off = 1; off < 1024; off <<= 1) {
    unsigned v = (tid >= off) ? sc[tid - off] : 0;
    __syncthreads();
    sc[tid] += v;
    __syncthreads();
  }
  unsigned excl = sc[tid] - packed;
  int gtb = (int)(excl >> 16), eqb = (int)(excl & 0xFFFFu);
  int orow = row * KK;
#pragma unroll
  for (int j = 0; j < 8; ++j) {
    bool isgt = kk[j] > T, iseq = kk[j] == T;
    bool take = isgt || (iseq && eqb < nEqTake);
    if (take) {
      int pos = gtb + (eqb < nEqTake ? eqb : nEqTake);
      idx[orow + pos] = base + j;
      gate[orow + pos] = (float)__longlong_as_double((long long)kk[j]);
    }
    gtb += isgt ? 1 : 0;
    eqb += iseq ? 1 : 0;
  }
}

// ---------------- inverse map: token -> list of global slots ----------------
__global__ __launch_bounds__(256) void buildinv_kernel(const int* __restrict__ idx,
                                                       int* __restrict__ cnt,
                                                       int* __restrict__ inv) {
  int s = blockIdx.x * 256 + threadIdx.x;
  int gp = s >> 11;
  int b = gp >> 3;
  int t = idx[s];
  int key = b * Ll + t;
  int pos = atomicAdd(&cnt[key], 1);
  inv[key * 8 + pos] = s;
}

// ---------------- combine: out[b,l,:] = sum over slots yout[slot,:] ----------------
__global__ __launch_bounds__(256) void combine_kernel(const _Float16* __restrict__ yout,
                                                      const int* __restrict__ cnt,
                                                      const int* __restrict__ inv,
                                                      float* __restrict__ out) {
  int tglob = blockIdx.x * 4 + (threadIdx.x >> 6);
  int lane = threadIdx.x & 63;
  int n = cnt[tglob];
  float acc[8];
#pragma unroll
  for (int j = 0; j < 8; ++j) acc[j] = 0.f;
  for (int c = 0; c < n; ++c) {
    int s = inv[tglob * 8 + c];
    u32x4 u = __builtin_nontemporal_load(
        reinterpret_cast<const u32x4*>(yout + (size_t)s * Hh + lane * 8));
    f16x8 v = *reinterpret_cast<f16x8*>(&u);
#pragma unroll
    for (int j = 0; j < 8; ++j) acc[j] += (float)v[j];
  }
  float* o = out + (size_t)tglob * Hh + lane * 8;
  f32x4 lo = {acc[0], acc[1], acc[2], acc[3]};
  f32x4 hi = {acc[4], acc[5], acc[6], acc[7]};
  __builtin_nontemporal_store(lo, reinterpret_cast<f32x4*>(o));
  __builtin_nontemporal_store(hi, reinterpret_cast<f32x4*>(o + 4));
}

// ---------------- GEMM1: hmid = gelu(gather(x) @ W1[e] + b1[e]) ----------------
// 256x256 tile, BK=64, 8 waves, 2-buffer LDS, stage-after-barrier prefetch.
// XCD-pinned per-round decode (pair rr*8+j on XCD j; A 2MB + B 1MB < 4MB L2).
// hmid epilogue stores nontemporal (r15/r16 A/B: cached stores evict pinned operands).
__global__ __launch_bounds__(512, 2) void gemm1_kernel(const _Float16* __restrict__ xb,
                                                       const _Float16* __restrict__ w1t,  // [E][F][H]
                                                       const float* __restrict__ b1,
                                                       const int* __restrict__ idx,
                                                       _Float16* __restrict__ hmid,  // [slot][2048][F]
                                                       int chunk_base) {
  __shared__ __align__(16) _Float16 lds[65536];  // 2 bufs x 32768 f16; epilogue: 256x256
  int tid = threadIdx.x, lane = tid & 63, wid = tid >> 6;
  int nat = blockIdx.x;
  int rr = nat >> 8;                 // round
  int j = nat & 7;                   // XCD
  int idxb = (nat >> 3) & 31;        // 0..31 within (round, XCD)
  int pl = rr * 8 + j;               // pair slot
  int bx = idxb & 3, by = idxb >> 2;
  int gp = chunk_base + pl;
  int b = gp >> 3, e = gp & 7;
  int m0 = by * 256, f0 = bx * 256;

  const _Float16* srcbase[8];
  int dstoff[8];
#pragma unroll
  for (int i = 0; i < 8; ++i) {
    int c = wid * 8 + i;
    int lr = (c & 31) * 8 + (lane >> 3);
    int q = lane & 7;
    int qg = q ^ (lr & 7);
    if (c < 32) {
      int token = idx[(size_t)gp * KK + m0 + lr];
      srcbase[i] = xb + ((size_t)b * Ll + token) * Hh + qg * 8;
      dstoff[i] = (c & 31) * 512;
    } else {
      srcbase[i] = w1t + ((size_t)e * Ff + f0 + lr) * Hh + qg * 8;
      dstoff[i] = 16384 + (c & 31) * 512;
    }
  }

  f32x4 acc[8][4] = {};
  int wm = wid >> 2, wn = wid & 3;
  int a_off[8], b_off[4];
  int ko = lane >> 4;
#pragma unroll
  for (int i = 0; i < 8; ++i) {
    int ra = wm * 128 + i * 16 + (lane & 15);
    a_off[i] = ra * 64 + (ko ^ (ra & 7)) * 8;
  }
#pragma unroll
  for (int i = 0; i < 4; ++i) {
    int rb = wn * 64 + i * 16 + (lane & 15);
    b_off[i] = 16384 + rb * 64 + (ko ^ (rb & 7)) * 8;
  }

  auto stage = [&](int p, int kt) {
#pragma unroll
    for (int i = 0; i < 8; ++i) {
      __builtin_amdgcn_global_load_lds(
          (const __attribute__((address_space(1))) void*)(srcbase[i] + kt),
          (__attribute__((address_space(3))) void*)(lds + p * 32768 + dstoff[i]), 16, 0, 0);
    }
  };

  constexpr int nt = Hh / 64;  // 8
  stage(0, 0);
  for (int t = 0; t < nt; ++t) {
    __syncthreads();  // drains stage(t) (in flight one full body) + prior reads retired
    if (t + 1 < nt) stage((t + 1) & 1, (t + 1) * 64);
    const _Float16* buf = lds + (t & 1) * 32768;
#pragma unroll
    for (int half = 0; half < 2; ++half) {
      int kx = half * 32;
      f16x8 af[8], bf[4];
#pragma unroll
      for (int i = 0; i < 8; ++i) af[i] = *reinterpret_cast<const f16x8*>(buf + (a_off[i] ^ kx));
#pragma unroll
      for (int i = 0; i < 4; ++i) bf[i] = *reinterpret_cast<const f16x8*>(buf + (b_off[i] ^ kx));
      __builtin_amdgcn_s_setprio(1);
#pragma unroll
      for (int fr = 0; fr < 8; ++fr)
#pragma unroll
        for (int fc = 0; fc < 4; ++fc)
          acc[fr][fc] = __builtin_amdgcn_mfma_f32_16x16x32_f16(af[fr], bf[fc], acc[fr][fc], 0, 0, 0);
      __builtin_amdgcn_s_setprio(0);
    }
  }
  __syncthreads();

  // epilogue: GELU, XOR-swizzled repack in LDS (256x256), nontemporal 16B stores
  int cidx = lane & 15, rbase = (lane >> 4) * 4;
  float b1v[4];
#pragma unroll
  for (int fc = 0; fc < 4; ++fc) b1v[fc] = b1[e * Ff + f0 + wn * 64 + fc * 16 + cidx];
#pragma unroll
  for (int fr = 0; fr < 8; ++fr) {
#pragma unroll
    for (int fc = 0; fc < 4; ++fc) {
#pragma unroll
      for (int r = 0; r < 4; ++r) {
        int lm = wm * 128 + fr * 16 + rbase + r;
        int lf = wn * 64 + fc * 16 + cidx;
        float v = acc[fr][fc][r] + b1v[fc];
        lds[lm * 256 + (((lf >> 3) ^ (lm & 7)) << 3) + (lf & 7)] = (_Float16)gelu_exact(v);
      }
    }
  }
  __syncthreads();
  _Float16* hd = hmid + (size_t)pl * KK * Ff;
  int orow = tid >> 5, seg = tid & 31;
#pragma unroll
  for (int pp = 0; pp < 16; ++pp) {
    int lm = pp * 16 + orow;
    f16x8 v = *reinterpret_cast<const f16x8*>(lds + lm * 256 + ((seg ^ (lm & 7)) << 3));
    nt_store16(v, hd + (size_t)(m0 + lm) * Ff + f0 + seg * 8);
  }
}

// ---------------- GEMM2: yout[slot,:] = gate * (hmid @ W2[e] + b2[e]) ----------------
// XCD-pinned combos (pair, h0): per 256-block round, XCD j owns 4 combos = 2 pairs x 2 h0:
// B (w2t) pinned in L2; each pair's hmid-A read by both h0-combos on the SAME XCD.
__global__ __launch_bounds__(512, 2) void gemm2_kernel(const _Float16* __restrict__ hmid,
                                                       const _Float16* __restrict__ w2t,  // [E][H][F]
                                                       const float* __restrict__ b2,
                                                       const int* __restrict__ idx,
                                                       const float* __restrict__ gate,
                                                       _Float16* __restrict__ yout,  // [64*2048][H]
                                                       int chunk_base, int small8) {
  __shared__ __align__(16) _Float16 lds[65536];
  int tid = threadIdx.x, lane = tid & 63, wid = tid >> 6;
  int nat = blockIdx.x;
  int ci, by;
  if (small8) {  // 128-block grid: 16 combos, 2 per XCD
    int j = nat & 7;
    int idxb = nat >> 3;
    ci = j * 2 + (idxb >> 3);
    by = idxb & 7;
  } else {       // 256-block rounds: 32 combos/round, 4 per XCD
    int rr = nat >> 8;
    int low = nat & 255;
    int j = low & 7;
    int idxb = low >> 3;
    ci = rr * 32 + j * 4 + (idxb >> 3);
    by = idxb & 7;
  }
  int pl = ci >> 1;
  int h0 = (ci & 1) * 256;
  int gp = chunk_base + pl;
  int e = gp & 7;
  int m0 = by * 256;

  const _Float16* srcbase[8];
  int dstoff[8];
#pragma unroll
  for (int i = 0; i < 8; ++i) {
    int c = wid * 8 + i;
    int lr = (c & 31) * 8 + (lane >> 3);
    int q = lane & 7;
    int qg = q ^ (lr & 7);
    if (c < 32) {
      srcbase[i] = hmid + ((size_t)pl * KK + m0 + lr) * Ff + qg * 8;
      dstoff[i] = (c & 31) * 512;
    } else {
      srcbase[i] = w2t + ((size_t)e * Hh + h0 + lr) * Ff + qg * 8;
      dstoff[i] = 16384 + (c & 31) * 512;
    }
  }

  f32x4 acc[8][4] = {};
  int wm = wid >> 2, wn = wid & 3;
  int a_off[8], b_off[4];
  int ko = lane >> 4;
#pragma unroll
  for (int i = 0; i < 8; ++i) {
    int ra = wm * 128 + i * 16 + (lane & 15);
    a_off[i] = ra * 64 + (ko ^ (ra & 7)) * 8;
  }
#pragma unroll
  for (int i = 0; i < 4; ++i) {
    int rb = wn * 64 + i * 16 + (lane & 15);
    b_off[i] = 16384 + rb * 64 + (ko ^ (rb & 7)) * 8;
  }

  auto stage = [&](int p, int kt) {
#pragma unroll
    for (int i = 0; i < 8; ++i) {
      __builtin_amdgcn_global_load_lds(
          (const __attribute__((address_space(1))) void*)(srcbase[i] + kt),
          (__attribute__((address_space(3))) void*)(lds + p * 32768 + dstoff[i]), 16, 0, 0);
    }
  };

  constexpr int nt = Ff / 64;  // 16
  stage(0, 0);
  for (int t = 0; t < nt; ++t) {
    __syncthreads();
    if (t + 1 < nt) stage((t + 1) & 1, (t + 1) * 64);
    const _Float16* buf = lds + (t & 1) * 32768;
#pragma unroll
    for (int half = 0; half < 2; ++half) {
      int kx = half * 32;
      f16x8 af[8], bf[4];
#pragma unroll
      for (int i = 0; i < 8; ++i) af[i] = *reinterpret_cast<const f16x8*>(buf + (a_off[i] ^ kx));
#pragma unroll
      for (int i = 0; i < 4; ++i) bf[i] = *reinterpret_cast<const f16x8*>(buf + (b_off[i] ^ kx));
      __builtin_amdgcn_s_setprio(1);
#pragma unroll
      for (int fr = 0; fr < 8; ++fr)
#pragma unroll
        for (int fc = 0; fc < 4; ++fc)
          acc[fr][fc] = __builtin_amdgcn_mfma_f32_16x16x32_f16(af[fr], bf[fc], acc[fr][fc], 0, 0, 0);
      __builtin_amdgcn_s_setprio(0);
    }
  }
  __syncthreads();

  // epilogue: apply b2 + gate weight, XOR-swizzled repack in LDS, nt 16B stores
  int cidx = lane & 15, rbase = (lane >> 4) * 4;
  float b2v[4];
#pragma unroll
  for (int fc = 0; fc < 4; ++fc) b2v[fc] = b2[e * Hh + h0 + wn * 64 + fc * 16 + cidx];
#pragma unroll
  for (int fr = 0; fr < 8; ++fr) {
    float gv[4];
#pragma unroll
    for (int r = 0; r < 4; ++r) {
      int lm = wm * 128 + fr * 16 + rbase + r;
      gv[r] = gate[(size_t)gp * KK + m0 + lm];
    }
#pragma unroll
    for (int fc = 0; fc < 4; ++fc) {
#pragma unroll
      for (int r = 0; r < 4; ++r) {
        int lm = wm * 128 + fr * 16 + rbase + r;
        int lh = wn * 64 + fc * 16 + cidx;
        float v = acc[fr][fc][r] + b2v[fc];
        lds[lm * 256 + (((lh >> 3) ^ (lm & 7)) << 3) + (lh & 7)] = (_Float16)(gv[r] * v);
      }
    }
  }
  __syncthreads();
  int orow = tid >> 5, seg = tid & 31;
#pragma unroll
  for (int pp = 0; pp < 16; ++pp) {
    int lm = pp * 16 + orow;
    f16x8 v = *reinterpret_cast<const f16x8*>(lds + lm * 256 + ((seg ^ (lm & 7)) << 3));
    nt_store16(v, yout + ((size_t)gp * KK + m0 + lm) * Hh + h0 + seg * 8);
  }
}

// ---------------- launcher ----------------
extern "C" void kernel_launch(void* const* d_in, const int* in_sizes, int n_in,
                              void* d_out, int out_size, void* d_ws, size_t ws_size,
                              hipStream_t stream) {
  const float* x  = (const float*)d_in[0];
  const float* Wg = (const float*)d_in[1];
  const float* W1 = (const float*)d_in[2];
  const float* b1 = (const float*)d_in[3];
  const float* W2 = (const float*)d_in[4];
  const float* b2 = (const float*)d_in[5];
  float* out = (float*)d_out;

  char* ws = (char*)d_ws;
  size_t off = 0;
  auto alloc = [&](size_t bytes) -> char* {
    char* p = ws + off;
    off = (off + bytes + 255) & ~(size_t)255;
    return p;
  };
  _Float16* xb   = (_Float16*)alloc((size_t)Bb * Ll * Hh * 2);
  _Float16* w1t  = (_Float16*)alloc((size_t)Ee * Ff * Hh * 2);
  _Float16* w2t  = (_Float16*)alloc((size_t)Ee * Hh * Ff * 2);
  double*   St   = (double*)alloc((size_t)Bb * Ee * Ll * 8);
  int*      dI   = (int*)alloc((size_t)Bb * Ee * KK * 4);
  float*    dG   = (float*)alloc((size_t)Bb * Ee * KK * 4);
  int*      cnt  = (int*)alloc((size_t)Bb * Ll * 4);
  int*      inv  = (int*)alloc((size_t)Bb * Ll * 8 * 4);
  _Float16* yout = (_Float16*)alloc((size_t)Bb * Ee * KK * Hh * 2);
  size_t fixed = off;
  size_t per_pair = (size_t)KK * Ff * 2;
  int chunk = 8;
  if (fixed + per_pair * 32 <= ws_size) chunk = 32;
  else if (fixed + per_pair * 16 <= ws_size) chunk = 16;
  _Float16* hmid = (_Float16*)alloc(per_pair * (size_t)chunk);

  hipMemsetAsync(cnt, 0, (size_t)Bb * Ll * 4, stream);
  gatecvt_kernel<<<Bb * Ll / 32, 256, 0, stream>>>(x, Wg, St, xb);
  transpose_cvt_kernel<<<dim3(Ff / 32, Hh / 32, Ee), dim3(32, 8), 0, stream>>>(W1, w1t, Hh, Ff);
  transpose_cvt_kernel<<<dim3(Hh / 32, Ff / 32, Ee), dim3(32, 8), 0, stream>>>(W2, w2t, Ff, Hh);
  topk_kernel<<<Bb * Ee, 1024, 0, stream>>>(St, dI, dG);
  buildinv_kernel<<<Bb * Ee * KK / 256, 256, 0, stream>>>(dI, cnt, inv);

  for (int cb = 0; cb < Bb * Ee; cb += chunk) {
    gemm1_kernel<<<chunk * 32, 512, 0, stream>>>(xb, w1t, b1, dI, hmid, cb);
    gemm2_kernel<<<chunk * 16, 512, 0, stream>>>(hmid, w2t, b2, dI, dG, yout, cb,
                                                 chunk == 8 ? 1 : 0);
  }
  combine_kernel<<<Bb * Ll / 4, 256, 0, stream>>>(yout, cnt, inv, out);
}

// Round 19
// 516.893 us; speedup vs baseline: 1.0131x; 1.0131x over previous
//
#include <hip/hip_runtime.h>
#include <hip/hip_bf16.h>
#include <hip/hip_fp16.h>

typedef float f32x4 __attribute__((ext_vector_type(4)));
typedef _Float16 f16x8 __attribute__((ext_vector_type(8)));
typedef unsigned int u32x4 __attribute__((ext_vector_type(4)));

static constexpr int Bb = 8, Ll = 8192, Hh = 512, Ee = 8, Ff = 1024, KK = 2048;

static __device__ __forceinline__ float fast_rcp(float x) {
#if __has_builtin(__builtin_amdgcn_rcpf)
  return __builtin_amdgcn_rcpf(x);
#else
  return 1.0f / x;
#endif
}

// exact GELU via Abramowitz-Stegun 7.1.25 erf approximation (|err| < 2.5e-5), branchless
static __device__ __forceinline__ float gelu_exact(float v) {
  float a = __builtin_fabsf(v) * 0.70710678118654752f;
  float t = fast_rcp(__builtin_fmaf(0.47047f, a, 1.0f));
  float p = __builtin_fmaf(0.7478556f, t, -0.0958798f);
  p = __builtin_fmaf(p, t, 0.3480242f);
  p = p * t;
  float e = __expf(-a * a);
  float er = __builtin_fmaf(-p, e, 1.0f);
  er = __builtin_copysignf(er, v);
  return 0.5f * v * (1.0f + er);
}

static __device__ __forceinline__ void nt_store16(const f16x8& v, _Float16* p) {
  __builtin_nontemporal_store(*reinterpret_cast<const u32x4*>(&v),
                              reinterpret_cast<u32x4*>(p));
}

// ---------------- transpose + convert: src[z][R][C] f32 -> dst[z][C][R] f16 ----------------
__global__ __launch_bounds__(256) void transpose_cvt_kernel(const float* __restrict__ src,
                                                            _Float16* __restrict__ dst,
                                                            int R, int C) {
  __shared__ float tile[32][33];
  int z = blockIdx.z;
  const float* s = src + (size_t)z * R * C;
  _Float16* d = dst + (size_t)z * R * C;
  int c0 = blockIdx.x * 32, r0 = blockIdx.y * 32;
  int tx = threadIdx.x, ty = threadIdx.y;
#pragma unroll
  for (int i = ty; i < 32; i += 8) tile[i][tx] = s[(size_t)(r0 + i) * C + (c0 + tx)];
  __syncthreads();
#pragma unroll
  for (int i = ty; i < 32; i += 8) d[(size_t)(c0 + i) * R + (r0 + tx)] = (_Float16)tile[tx][i];
}

// ------ fused gate + x->f16 convert; 8 independent fp64 chains, 128-wide chunks ------
__global__ __launch_bounds__(256) void gatecvt_kernel(const float* __restrict__ x,
                                                      const float* __restrict__ Wg,
                                                      double* __restrict__ St,
                                                      _Float16* __restrict__ xb) {
  __shared__ float wgt[8][516];  // Wg transposed, row-padded
  __shared__ float xs[32][132];  // 32 tokens x 128-col chunk, row-padded
  int tid = threadIdx.x;
  for (int i = tid; i < Hh * Ee; i += 256) wgt[i & 7][i >> 3] = Wg[i];
  int row = tid >> 3, seg = tid & 7;
  int token0 = blockIdx.x * 32;
  const float* xrow = x + (size_t)(token0 + row) * Hh;
  _Float16* xbrow = xb + (size_t)(token0 + row) * Hh;
  float4 r0 = reinterpret_cast<const float4*>(xrow)[seg * 4 + 0];
  float4 r1 = reinterpret_cast<const float4*>(xrow)[seg * 4 + 1];
  float4 r2 = reinterpret_cast<const float4*>(xrow)[seg * 4 + 2];
  float4 r3 = reinterpret_cast<const float4*>(xrow)[seg * 4 + 3];
  double a0 = 0.0, a1 = 0.0, a2 = 0.0, a3 = 0.0;  // 8 independent fp64 chains
  double a4 = 0.0, a5 = 0.0, a6 = 0.0, a7 = 0.0;
  for (int c = 0; c < 4; ++c) {
    f16x8 h0, h1;
    h0[0] = (_Float16)r0.x; h0[1] = (_Float16)r0.y; h0[2] = (_Float16)r0.z; h0[3] = (_Float16)r0.w;
    h0[4] = (_Float16)r1.x; h0[5] = (_Float16)r1.y; h0[6] = (_Float16)r1.z; h0[7] = (_Float16)r1.w;
    h1[0] = (_Float16)r2.x; h1[1] = (_Float16)r2.y; h1[2] = (_Float16)r2.z; h1[3] = (_Float16)r2.w;
    h1[4] = (_Float16)r3.x; h1[5] = (_Float16)r3.y; h1[6] = (_Float16)r3.z; h1[7] = (_Float16)r3.w;
    nt_store16(h0, xbrow + c * 128 + seg * 16);
    nt_store16(h1, xbrow + c * 128 + seg * 16 + 8);
    __syncthreads();
    *reinterpret_cast<float4*>(&xs[row][seg * 16 + 0]) = r0;
    *reinterpret_cast<float4*>(&xs[row][seg * 16 + 4]) = r1;
    *reinterpret_cast<float4*>(&xs[row][seg * 16 + 8]) = r2;
    *reinterpret_cast<float4*>(&xs[row][seg * 16 + 12]) = r3;
    if (c + 1 < 4) {
      const float4* nx = reinterpret_cast<const float4*>(xrow + (c + 1) * 128);
      r0 = nx[seg * 4 + 0]; r1 = nx[seg * 4 + 1]; r2 = nx[seg * 4 + 2]; r3 = nx[seg * 4 + 3];
    }
    __syncthreads();
#pragma unroll
    for (int hh = 0; hh < 128; hh += 8) {
      float4 xv = *reinterpret_cast<const float4*>(&xs[row][hh]);
      float4 wv = *reinterpret_cast<const float4*>(&wgt[seg][c * 128 + hh]);
      a0 += (double)xv.x * (double)wv.x;
      a1 += (double)xv.y * (double)wv.y;
      a2 += (double)xv.z * (double)wv.z;
      a3 += (double)xv.w * (double)wv.w;
      float4 xw = *reinterpret_cast<const float4*>(&xs[row][hh + 4]);
      float4 ww = *reinterpret_cast<const float4*>(&wgt[seg][c * 128 + hh + 4]);
      a4 += (double)xw.x * (double)ww.x;
      a5 += (double)xw.y * (double)ww.y;
      a6 += (double)xw.z * (double)ww.z;
      a7 += (double)xw.w * (double)ww.w;
    }
  }
  double acc = ((a0 + a1) + (a2 + a3)) + ((a4 + a5) + (a6 + a7));
  double m = acc;
  m = fmax(m, __shfl_xor(m, 1, 64));
  m = fmax(m, __shfl_xor(m, 2, 64));
  m = fmax(m, __shfl_xor(m, 4, 64));
  double ex = exp(acc - m);
  double s = ex;
  s += __shfl_xor(s, 1, 64);
  s += __shfl_xor(s, 2, 64);
  s += __shfl_xor(s, 4, 64);
  int token = token0 + row;
  int b = token >> 13, l = token & (Ll - 1);
  St[((size_t)(b * Ee + seg)) * Ll + l] = ex / s;
}

// ---------------- top-k (k=2048) per (b,e) row, jax.lax.top_k tie semantics ----------------
__global__ __launch_bounds__(1024) void topk_kernel(const double* __restrict__ St,
                                                    int* __restrict__ idx,
                                                    float* __restrict__ gate) {
  __shared__ unsigned long long keys[Ll];
  __shared__ unsigned int hist[256];
  __shared__ unsigned int sc[1024];
  __shared__ unsigned long long s_prefix;
  __shared__ int s_remaining;
  __shared__ unsigned long long redA[16], redO[16];
  int row = blockIdx.x;
  int tid = threadIdx.x;
  const double* s = St + (size_t)row * Ll;
  unsigned long long myA = ~0ULL, myO = 0ULL;
  for (int i = tid; i < Ll; i += 1024) {
    unsigned long long kx = (unsigned long long)__double_as_longlong(s[i]);
    keys[i] = kx;
    myA &= kx;
    myO |= kx;
  }
#pragma unroll
  for (int off2 = 32; off2 >= 1; off2 >>= 1) {
    myA &= __shfl_xor(myA, off2, 64);
    myO |= __shfl_xor(myO, off2, 64);
  }
  if ((tid & 63) == 0) { redA[tid >> 6] = myA; redO[tid >> 6] = myO; }
  __syncthreads();
  unsigned long long allA = redA[0], allO = redO[0];
#pragma unroll
  for (int w = 1; w < 16; ++w) { allA &= redA[w]; allO |= redO[w]; }
  unsigned long long diff = allA ^ allO;

  unsigned long long T;
  int nEqTake;
  if (diff == 0) {
    T = allA;
    nEqTake = KK;
  } else {
    int hb = 63 - __builtin_clzll(diff);
    int pv = hb >> 3;
    unsigned long long prefmask = (pv >= 7) ? 0ULL : (~0ULL << ((pv + 1) * 8));
    unsigned long long prefix = allA & prefmask;
    int remaining = KK;
    for (int p = pv; p >= 0; --p) {
      if (tid < 256) hist[tid] = 0;
      __syncthreads();
      int sh = p * 8;
      for (int i = tid; i < Ll; i += 1024) {
        unsigned long long kk = keys[i];
        if ((kk & prefmask) == prefix) atomicAdd(&hist[(unsigned)(kk >> sh) & 255u], 1u);
      }
      __syncthreads();
      if (tid < 256) sc[tid] = hist[tid];
      __syncthreads();
#pragma unroll
      for (int off = 1; off < 256; off <<= 1) {
        unsigned v = (tid < 256 && tid + off < 256) ? sc[tid + off] : 0;
        __syncthreads();
        if (tid < 256) sc[tid] += v;
        __syncthreads();
      }
      if (tid < 256) {
        unsigned incl = sc[tid];
        unsigned above = (tid == 255) ? 0u : sc[tid + 1];
        if ((int)incl >= remaining && (int)above < remaining) {
          s_remaining = remaining - (int)above;
          s_prefix = prefix | ((unsigned long long)(unsigned)tid << sh);
        }
      }
      __syncthreads();
      remaining = s_remaining;
      prefix = s_prefix;
      prefmask |= (255ULL << sh);
      __syncthreads();
    }
    T = prefix;
    nEqTake = remaining;
  }

  int base = tid * 8;
  unsigned long long kk[8];
  unsigned gtc = 0, eqc = 0;
#pragma unroll
  for (int j = 0; j < 8; ++j) {
    kk[j] = keys[base + j];
    gtc += (kk[j] > T);
    eqc += (kk[j] == T);
  }
  unsigned packed = (gtc << 16) | eqc;
  sc[tid] = packed;
  __syncthreads();
  for (int off = 1; off < 1024; off <<= 1) {
    unsigned v = (tid >= off) ? sc[tid - off] : 0;
    __syncthreads();
    sc[tid] += v;
    __syncthreads();
  }
  unsigned excl = sc[tid] - packed;
  int gtb = (int)(excl >> 16), eqb = (int)(excl & 0xFFFFu);
  int orow = row * KK;
#pragma unroll
  for (int j = 0; j < 8; ++j) {
    bool isgt = kk[j] > T, iseq = kk[j] == T;
    bool take = isgt || (iseq && eqb < nEqTake);
    if (take) {
      int pos = gtb + (eqb < nEqTake ? eqb : nEqTake);
      idx[orow + pos] = base + j;
      gate[orow + pos] = (float)__longlong_as_double((long long)kk[j]);
    }
    gtb += isgt ? 1 : 0;
    eqb += iseq ? 1 : 0;
  }
}

// ---------------- inverse map: token -> list of global slots ----------------
__global__ __launch_bounds__(256) void buildinv_kernel(const int* __restrict__ idx,
                                                       int* __restrict__ cnt,
                                                       int* __restrict__ inv) {
  int s = blockIdx.x * 256 + threadIdx.x;
  int gp = s >> 11;
  int b = gp >> 3;
  int t = idx[s];
  int key = b * Ll + t;
  int pos = atomicAdd(&cnt[key], 1);
  inv[key * 8 + pos] = s;
}

// ---------------- combine: out[b,l,:] = sum over slots yout[slot,:] ----------------
__global__ __launch_bounds__(256) void combine_kernel(const _Float16* __restrict__ yout,
                                                      const int* __restrict__ cnt,
                                                      const int* __restrict__ inv,
                                                      float* __restrict__ out) {
  int tglob = blockIdx.x * 4 + (threadIdx.x >> 6);
  int lane = threadIdx.x & 63;
  int n = cnt[tglob];
  float acc[8];
#pragma unroll
  for (int j = 0; j < 8; ++j) acc[j] = 0.f;
  for (int c = 0; c < n; ++c) {
    int s = inv[tglob * 8 + c];
    u32x4 u = __builtin_nontemporal_load(
        reinterpret_cast<const u32x4*>(yout + (size_t)s * Hh + lane * 8));
    f16x8 v = *reinterpret_cast<f16x8*>(&u);
#pragma unroll
    for (int j = 0; j < 8; ++j) acc[j] += (float)v[j];
  }
  float* o = out + (size_t)tglob * Hh + lane * 8;
  f32x4 lo = {acc[0], acc[1], acc[2], acc[3]};
  f32x4 hi = {acc[4], acc[5], acc[6], acc[7]};
  __builtin_nontemporal_store(lo, reinterpret_cast<f32x4*>(o));
  __builtin_nontemporal_store(hi, reinterpret_cast<f32x4*>(o + 4));
}

// ---------------- GEMM1: hmid = gelu(gather(x) @ W1[e] + b1[e]) ----------------
// 256x256 tile, BK=64, 8 waves, 2-buffer LDS, stage-after-barrier prefetch.
// XCD-pinned per-round decode (pair rr*8+j on XCD j; A 2MB + B 1MB < 4MB L2).
// hmid epilogue stores nontemporal (r15/r16 A/B: cached stores evict pinned operands).
__global__ __launch_bounds__(512, 2) void gemm1_kernel(const _Float16* __restrict__ xb,
                                                       const _Float16* __restrict__ w1t,  // [E][F][H]
                                                       const float* __restrict__ b1,
                                                       const int* __restrict__ idx,
                                                       _Float16* __restrict__ hmid,  // [slot][2048][F]
                                                       int chunk_base) {
  __shared__ __align__(16) _Float16 lds[65536];  // 2 bufs x 32768 f16; epilogue: 256x256
  int tid = threadIdx.x, lane = tid & 63, wid = tid >> 6;
  int nat = blockIdx.x;
  int rr = nat >> 8;                 // round
  int j = nat & 7;                   // XCD
  int idxb = (nat >> 3) & 31;        // 0..31 within (round, XCD)
  int pl = rr * 8 + j;               // pair slot
  int bx = idxb & 3, by = idxb >> 2;
  int gp = chunk_base + pl;
  int b = gp >> 3, e = gp & 7;
  int m0 = by * 256, f0 = bx * 256;

  const _Float16* srcbase[8];
  int dstoff[8];
#pragma unroll
  for (int i = 0; i < 8; ++i) {
    int c = wid * 8 + i;
    int lr = (c & 31) * 8 + (lane >> 3);
    int q = lane & 7;
    int qg = q ^ (lr & 7);
    if (c < 32) {
      int token = idx[(size_t)gp * KK + m0 + lr];
      srcbase[i] = xb + ((size_t)b * Ll + token) * Hh + qg * 8;
      dstoff[i] = (c & 31) * 512;
    } else {
      srcbase[i] = w1t + ((size_t)e * Ff + f0 + lr) * Hh + qg * 8;
      dstoff[i] = 16384 + (c & 31) * 512;
    }
  }

  f32x4 acc[8][4] = {};
  int wm = wid >> 2, wn = wid & 3;
  int a_off[8], b_off[4];
  int ko = lane >> 4;
#pragma unroll
  for (int i = 0; i < 8; ++i) {
    int ra = wm * 128 + i * 16 + (lane & 15);
    a_off[i] = ra * 64 + (ko ^ (ra & 7)) * 8;
  }
#pragma unroll
  for (int i = 0; i < 4; ++i) {
    int rb = wn * 64 + i * 16 + (lane & 15);
    b_off[i] = 16384 + rb * 64 + (ko ^ (rb & 7)) * 8;
  }

  auto stage = [&](int p, int kt) {
#pragma unroll
    for (int i = 0; i < 8; ++i) {
      __builtin_amdgcn_global_load_lds(
          (const __attribute__((address_space(1))) void*)(srcbase[i] + kt),
          (__attribute__((address_space(3))) void*)(lds + p * 32768 + dstoff[i]), 16, 0, 0);
    }
  };

  constexpr int nt = Hh / 64;  // 8
  stage(0, 0);
  for (int t = 0; t < nt; ++t) {
    __syncthreads();  // drains stage(t) (in flight one full body) + prior reads retired
    if (t + 1 < nt) stage((t + 1) & 1, (t + 1) * 64);
    const _Float16* buf = lds + (t & 1) * 32768;
#pragma unroll
    for (int half = 0; half < 2; ++half) {
      int kx = half * 32;
      f16x8 af[8], bf[4];
#pragma unroll
      for (int i = 0; i < 8; ++i) af[i] = *reinterpret_cast<const f16x8*>(buf + (a_off[i] ^ kx));
#pragma unroll
      for (int i = 0; i < 4; ++i) bf[i] = *reinterpret_cast<const f16x8*>(buf + (b_off[i] ^ kx));
      __builtin_amdgcn_s_setprio(1);
#pragma unroll
      for (int fr = 0; fr < 8; ++fr)
#pragma unroll
        for (int fc = 0; fc < 4; ++fc)
          acc[fr][fc] = __builtin_amdgcn_mfma_f32_16x16x32_f16(af[fr], bf[fc], acc[fr][fc], 0, 0, 0);
      __builtin_amdgcn_s_setprio(0);
    }
  }
  __syncthreads();

  // epilogue: GELU, XOR-swizzled repack in LDS (256x256), nontemporal 16B stores
  int cidx = lane & 15, rbase = (lane >> 4) * 4;
  float b1v[4];
#pragma unroll
  for (int fc = 0; fc < 4; ++fc) b1v[fc] = b1[e * Ff + f0 + wn * 64 + fc * 16 + cidx];
#pragma unroll
  for (int fr = 0; fr < 8; ++fr) {
#pragma unroll
    for (int fc = 0; fc < 4; ++fc) {
#pragma unroll
      for (int r = 0; r < 4; ++r) {
        int lm = wm * 128 + fr * 16 + rbase + r;
        int lf = wn * 64 + fc * 16 + cidx;
        float v = acc[fr][fc][r] + b1v[fc];
        lds[lm * 256 + (((lf >> 3) ^ (lm & 7)) << 3) + (lf & 7)] = (_Float16)gelu_exact(v);
      }
    }
  }
  __syncthreads();
  _Float16* hd = hmid + (size_t)pl * KK * Ff;
  int orow = tid >> 5, seg = tid & 31;
#pragma unroll
  for (int pp = 0; pp < 16; ++pp) {
    int lm = pp * 16 + orow;
    f16x8 v = *reinterpret_cast<const f16x8*>(lds + lm * 256 + ((seg ^ (lm & 7)) << 3));
    nt_store16(v, hd + (size_t)(m0 + lm) * Ff + f0 + seg * 8);
  }
}

// ---------------- GEMM2: yout[slot,:] = gate * (hmid @ W2[e] + b2[e]) ----------------
// XCD-pinned combos (pair, h0): per 256-block round, XCD j owns 4 combos = 2 pairs x 2 h0:
// B (w2t) pinned in L2; each pair's hmid-A read by both h0-combos on the SAME XCD.
__global__ __launch_bounds__(512, 2) void gemm2_kernel(const _Float16* __restrict__ hmid,
                                                       const _Float16* __restrict__ w2t,  // [E][H][F]
                                                       const float* __restrict__ b2,
                                                       const int* __restrict__ idx,
                                                       const float* __restrict__ gate,
                                                       _Float16* __restrict__ yout,  // [64*2048][H]
                                                       int chunk_base, int small8) {
  __shared__ __align__(16) _Float16 lds[65536];
  int tid = threadIdx.x, lane = tid & 63, wid = tid >> 6;
  int nat = blockIdx.x;
  int ci, by;
  if (small8) {  // 128-block grid: 16 combos, 2 per XCD
    int j = nat & 7;
    int idxb = nat >> 3;
    ci = j * 2 + (idxb >> 3);
    by = idxb & 7;
  } else {       // 256-block rounds: 32 combos/round, 4 per XCD
    int rr = nat >> 8;
    int low = nat & 255;
    int j = low & 7;
    int idxb = low >> 3;
    ci = rr * 32 + j * 4 + (idxb >> 3);
    by = idxb & 7;
  }
  int pl = ci >> 1;
  int h0 = (ci & 1) * 256;
  int gp = chunk_base + pl;
  int e = gp & 7;
  int m0 = by * 256;

  const _Float16* srcbase[8];
  int dstoff[8];
#pragma unroll
  for (int i = 0; i < 8; ++i) {
    int c = wid * 8 + i;
    int lr = (c & 31) * 8 + (lane >> 3);
    int q = lane & 7;
    int qg = q ^ (lr & 7);
    if (c < 32) {
      srcbase[i] = hmid + ((size_t)pl * KK + m0 + lr) * Ff + qg * 8;
      dstoff[i] = (c & 31) * 512;
    } else {
      srcbase[i] = w2t + ((size_t)e * Hh + h0 + lr) * Ff + qg * 8;
      dstoff[i] = 16384 + (c & 31) * 512;
    }
  }

  f32x4 acc[8][4] = {};
  int wm = wid >> 2, wn = wid & 3;
  int a_off[8], b_off[4];
  int ko = lane >> 4;
#pragma unroll
  for (int i = 0; i < 8; ++i) {
    int ra = wm * 128 + i * 16 + (lane & 15);
    a_off[i] = ra * 64 + (ko ^ (ra & 7)) * 8;
  }
#pragma unroll
  for (int i = 0; i < 4; ++i) {
    int rb = wn * 64 + i * 16 + (lane & 15);
    b_off[i] = 16384 + rb * 64 + (ko ^ (rb & 7)) * 8;
  }

  auto stage = [&](int p, int kt) {
#pragma unroll
    for (int i = 0; i < 8; ++i) {
      __builtin_amdgcn_global_load_lds(
          (const __attribute__((address_space(1))) void*)(srcbase[i] + kt),
          (__attribute__((address_space(3))) void*)(lds + p * 32768 + dstoff[i]), 16, 0, 0);
    }
  };

  constexpr int nt = Ff / 64;  // 16
  stage(0, 0);
  for (int t = 0; t < nt; ++t) {
    __syncthreads();
    if (t + 1 < nt) stage((t + 1) & 1, (t + 1) * 64);
    const _Float16* buf = lds + (t & 1) * 32768;
#pragma unroll
    for (int half = 0; half < 2; ++half) {
      int kx = half * 32;
      f16x8 af[8], bf[4];
#pragma unroll
      for (int i = 0; i < 8; ++i) af[i] = *reinterpret_cast<const f16x8*>(buf + (a_off[i] ^ kx));
#pragma unroll
      for (int i = 0; i < 4; ++i) bf[i] = *reinterpret_cast<const f16x8*>(buf + (b_off[i] ^ kx));
      __builtin_amdgcn_s_setprio(1);
#pragma unroll
      for (int fr = 0; fr < 8; ++fr)
#pragma unroll
        for (int fc = 0; fc < 4; ++fc)
          acc[fr][fc] = __builtin_amdgcn_mfma_f32_16x16x32_f16(af[fr], bf[fc], acc[fr][fc], 0, 0, 0);
      __builtin_amdgcn_s_setprio(0);
    }
  }
  __syncthreads();

  // epilogue: apply b2 + gate weight, XOR-swizzled repack in LDS, nt 16B stores
  int cidx = lane & 15, rbase = (lane >> 4) * 4;
  float b2v[4];
#pragma unroll
  for (int fc = 0; fc < 4; ++fc) b2v[fc] = b2[e * Hh + h0 + wn * 64 + fc * 16 + cidx];
#pragma unroll
  for (int fr = 0; fr < 8; ++fr) {
    float gv[4];
#pragma unroll
    for (int r = 0; r < 4; ++r) {
      int lm = wm * 128 + fr * 16 + rbase + r;
      gv[r] = gate[(size_t)gp * KK + m0 + lm];
    }
#pragma unroll
    for (int fc = 0; fc < 4; ++fc) {
#pragma unroll
      for (int r = 0; r < 4; ++r) {
        int lm = wm * 128 + fr * 16 + rbase + r;
        int lh = wn * 64 + fc * 16 + cidx;
        float v = acc[fr][fc][r] + b2v[fc];
        lds[lm * 256 + (((lh >> 3) ^ (lm & 7)) << 3) + (lh & 7)] = (_Float16)(gv[r] * v);
      }
    }
  }
  __syncthreads();
  int orow = tid >> 5, seg = tid & 31;
#pragma unroll
  for (int pp = 0; pp < 16; ++pp) {
    int lm = pp * 16 + orow;
    f16x8 v = *reinterpret_cast<const f16x8*>(lds + lm * 256 + ((seg ^ (lm & 7)) << 3));
    nt_store16(v, yout + ((size_t)gp * KK + m0 + lm) * Hh + h0 + seg * 8);
  }
}

// ---------------- launcher ----------------
extern "C" void kernel_launch(void* const* d_in, const int* in_sizes, int n_in,
                              void* d_out, int out_size, void* d_ws, size_t ws_size,
                              hipStream_t stream) {
  const float* x  = (const float*)d_in[0];
  const float* Wg = (const float*)d_in[1];
  const float* W1 = (const float*)d_in[2];
  const float* b1 = (const float*)d_in[3];
  const float* W2 = (const float*)d_in[4];
  const float* b2 = (const float*)d_in[5];
  float* out = (float*)d_out;

  char* ws = (char*)d_ws;
  size_t off = 0;
  auto alloc = [&](size_t bytes) -> char* {
    char* p = ws + off;
    off = (off + bytes + 255) & ~(size_t)255;
    return p;
  };
  _Float16* xb   = (_Float16*)alloc((size_t)Bb * Ll * Hh * 2);
  _Float16* w1t  = (_Float16*)alloc((size_t)Ee * Ff * Hh * 2);
  _Float16* w2t  = (_Float16*)alloc((size_t)Ee * Hh * Ff * 2);
  double*   St   = (double*)alloc((size_t)Bb * Ee * Ll * 8);
  int*      dI   = (int*)alloc((size_t)Bb * Ee * KK * 4);
  float*    dG   = (float*)alloc((size_t)Bb * Ee * KK * 4);
  int*      cnt  = (int*)alloc((size_t)Bb * Ll * 4);
  int*      inv  = (int*)alloc((size_t)Bb * Ll * 8 * 4);
  _Float16* yout = (_Float16*)alloc((size_t)Bb * Ee * KK * Hh * 2);
  size_t fixed = off;
  size_t per_pair = (size_t)KK * Ff * 2;
  int chunk = 8;
  if (fixed + per_pair * 64 <= ws_size) chunk = 64;
  else if (fixed + per_pair * 32 <= ws_size) chunk = 32;
  else if (fixed + per_pair * 16 <= ws_size) chunk = 16;
  _Float16* hmid = (_Float16*)alloc(per_pair * (size_t)chunk);

  hipMemsetAsync(cnt, 0, (size_t)Bb * Ll * 4, stream);
  gatecvt_kernel<<<Bb * Ll / 32, 256, 0, stream>>>(x, Wg, St, xb);
  transpose_cvt_kernel<<<dim3(Ff / 32, Hh / 32, Ee), dim3(32, 8), 0, stream>>>(W1, w1t, Hh, Ff);
  transpose_cvt_kernel<<<dim3(Hh / 32, Ff / 32, Ee), dim3(32, 8), 0, stream>>>(W2, w2t, Ff, Hh);
  topk_kernel<<<Bb * Ee, 1024, 0, stream>>>(St, dI, dG);
  buildinv_kernel<<<Bb * Ee * KK / 256, 256, 0, stream>>>(dI, cnt, inv);

  for (int cb = 0; cb < Bb * Ee; cb += chunk) {
    gemm1_kernel<<<chunk * 32, 512, 0, stream>>>(xb, w1t, b1, dI, hmid, cb);
    gemm2_kernel<<<chunk * 16, 512, 0, stream>>>(hmid, w2t, b2, dI, dG, yout, cb,
                                                 chunk == 8 ? 1 : 0);
  }
  combine_kernel<<<Bb * Ll / 4, 256, 0, stream>>>(yout, cnt, inv, out);
}